// Round 5
// baseline (402.338 us; speedup 1.0000x reference)
//
#include <hip/hip_runtime.h>

static constexpr int NN = 100000;    // nodes
static constexpr int NH = NN / 2;    // src-half boundary
static constexpr int NNH2 = NN / 2;  // dst-range size for L1 partial passes
static constexpr int EE = 1600000;   // edges (before self-loops)
static constexpr int BSZ = 64;       // nodes per bucket
static constexpr int NB = (NN + BSZ - 1) / BSZ;   // 1563 buckets
static constexpr int BCAP = 2048;    // fixed bucket capacity (mean 1024, 32 sigma)
static constexpr int TILE = 2048;    // edges per binning block
static constexpr int GB = 2048;      // gather blocks (persistent: 8 blocks/CU)

// ---- bf16 helpers (storage-only; math stays fp32) ----

__device__ __forceinline__ unsigned short f2bf(float f) {   // round-to-nearest-even
    unsigned u = __float_as_uint(f);
    u += 0x7FFFu + ((u >> 16) & 1u);
    return (unsigned short)(u >> 16);
}
__device__ __forceinline__ float bfl(unsigned u) { return __uint_as_float(u << 16); }
__device__ __forceinline__ float bfh(unsigned u) { return __uint_as_float(u & 0xFFFF0000u); }

typedef __attribute__((ext_vector_type(8))) short short8;    // 8 bf16 (4 VGPRs)
typedef __attribute__((ext_vector_type(4))) float float4v;   // MFMA acc
typedef __attribute__((ext_vector_type(4))) float float4n;   // nt vector

// ---------------- init: W^T bf16 prep + bucket cursor bases ----------------

__global__ __launch_bounds__(256) void k_init(const float* __restrict__ W1,
                                              const float* __restrict__ W2,
                                              unsigned short* __restrict__ W1t,
                                              unsigned short* __restrict__ W2t,
                                              int* __restrict__ bcur) {
    int idx = blockIdx.x * 256 + threadIdx.x;
    if (idx < 16384) {
        int n = idx >> 7, k = idx & 127;
        W1t[idx] = f2bf(W1[k * 128 + n]);
    } else if (idx < 24576) {
        int j = idx - 16384;
        int n = j >> 7, k = j & 127;
        W2t[j] = f2bf(W2[k * 64 + n]);
    } else if (idx < 24576 + NB) {
        int b = idx - 24576;
        bcur[b] = b * BCAP;
    }
}

// ---------------- bin edges into fixed-stride bucket chunks ----------------

__global__ __launch_bounds__(256) void k_bin(const int* __restrict__ src,
                                             const int* __restrict__ dst,
                                             int* __restrict__ bcur,
                                             int* __restrict__ ebuf, int E) {
    constexpr int K = TILE / 256;  // 8 edges per thread
    __shared__ int lcnt[NB];
    __shared__ int lbase[NB];
    const int t = threadIdx.x;
    const int e0 = blockIdx.x * TILE;

    for (int i = t; i < NB; i += 256) lcnt[i] = 0;
    __syncthreads();

    int dreg[K], ofs[K];
#pragma unroll
    for (int k = 0; k < K; ++k) {
        int e = e0 + k * 256 + t;
        if (e < E) {
            int d = dst[e];
            dreg[k] = d;
            ofs[k] = atomicAdd(&lcnt[d >> 6], 1);
        } else dreg[k] = -1;
    }
    __syncthreads();

    for (int i = t; i < NB; i += 256) {
        int c = lcnt[i];
        lbase[i] = c ? atomicAdd(&bcur[i], c) : 0;
    }
    __syncthreads();

#pragma unroll
    for (int k = 0; k < K; ++k) {
        if (dreg[k] >= 0) {
            int e = e0 + k * 256 + t;
            int s = src[e];
            int b = dreg[k] >> 6;
            ebuf[lbase[b] + ofs[k]] = (s << 6) | (dreg[k] & 63);
        }
    }
}

// ---------------- per-bucket: two-segment CSR (src<NH | src>=NH) ----------

__global__ __launch_bounds__(256) void k_csr(const int* __restrict__ bcur,
                                             const int* __restrict__ ebuf,
                                             int2* __restrict__ seg0,
                                             int2* __restrict__ seg1,
                                             float* __restrict__ dinv,
                                             int* __restrict__ csr, int n) {
    __shared__ int lcnt_lo[BSZ], lcnt_hi[BSZ];
    __shared__ int lofs_lo[BSZ], lofs_hi[BSZ];
    const int b = blockIdx.x, t = threadIdx.x;
    if (t < BSZ) { lcnt_lo[t] = 0; lcnt_hi[t] = 0; }
    __syncthreads();
    const int beg = b * BCAP, end = bcur[b];
    for (int j = beg + t; j < end; j += 256) {
        int e = ebuf[j];
        if ((e >> 6) < NH) atomicAdd(&lcnt_lo[e & 63], 1);
        else               atomicAdd(&lcnt_hi[e & 63], 1);
    }
    __syncthreads();
    if (t < BSZ) {                       // wave 0 only (threads 0..63)
        int lo = lcnt_lo[t], hi = lcnt_hi[t], c = lo + hi;
        int x = c;
#pragma unroll
        for (int off = 1; off < 64; off <<= 1) {
            int y = __shfl_up(x, off, 64);
            if (t >= off) x += y;
        }
        int exc = x - c;                 // exclusive prefix within bucket
        int node = b * BSZ + t;
        if (node < n) {
            seg0[node] = make_int2(beg + exc, beg + exc + lo);
            seg1[node] = make_int2(beg + exc + lo, beg + exc + c);
            dinv[node] = rsqrtf((float)c + 1.0f);   // +1 self-loop
        }
        lofs_lo[t] = beg + exc;
        lofs_hi[t] = beg + exc + lo;
    }
    __syncthreads();
    for (int j = beg + t; j < end; j += 256) {
        int e = ebuf[j];
        int d = e & 63, s = e >> 6;
        int pos = atomicAdd((s < NH) ? &lofs_lo[d] : &lofs_hi[d], 1);
        csr[pos] = s;
    }
}

// ---------------- MFMA GEMM layer 1: G = bf16((X @ W1) * dinv[row]) --------
// Output SLAB-MAJOR: 4 slabs of 32 cols; slab s = [N][8] uint2 (64 B/row).

__global__ __launch_bounds__(256) void k_gemm128m(const float* __restrict__ X,
                                                  const unsigned short* __restrict__ W1t,
                                                  const float* __restrict__ dinv,
                                                  unsigned* __restrict__ G, int M) {
    __shared__ float cls[4 * 16 * 132];
    const int t = threadIdx.x;
    const int w = t >> 6, lane = t & 63;
    const int quad = lane >> 4, m16 = lane & 15;
    const int row0 = blockIdx.x * 64 + w * 16;
    int arow = row0 + m16; if (arow >= M) arow = M - 1;

    short8 afrag[4];
#pragma unroll
    for (int ks = 0; ks < 4; ++ks) {
        const float* p = X + (size_t)arow * 128 + ks * 32 + quad * 8;
        float4 u0 = ((const float4*)p)[0];
        float4 u1 = ((const float4*)p)[1];
        short8 a;
        a[0] = (short)f2bf(u0.x); a[1] = (short)f2bf(u0.y);
        a[2] = (short)f2bf(u0.z); a[3] = (short)f2bf(u0.w);
        a[4] = (short)f2bf(u1.x); a[5] = (short)f2bf(u1.y);
        a[6] = (short)f2bf(u1.z); a[7] = (short)f2bf(u1.w);
        afrag[ks] = a;
    }
    float* myc = cls + w * 16 * 132;
#pragma unroll
    for (int nt = 0; nt < 8; ++nt) {
        float4v acc = {0.f, 0.f, 0.f, 0.f};
#pragma unroll
        for (int ks = 0; ks < 4; ++ks) {
            const short8 b = *((const short8*)(W1t + (size_t)(nt * 16 + m16) * 128 + ks * 32 + quad * 8));
            acc = __builtin_amdgcn_mfma_f32_16x16x32_bf16(afrag[ks], b, acc, 0, 0, 0);
        }
#pragma unroll
        for (int r = 0; r < 4; ++r)
            myc[(quad * 4 + r) * 132 + nt * 16 + m16] = acc[r];
    }
    __syncthreads();
    // pack + store into slab-major layout: slab = c>>3, chunk = c&7
#pragma unroll
    for (int i = 0; i < 8; ++i) {
        int idx = i * 64 + lane;
        int r = idx >> 5, c = idx & 31;
        int grow = row0 + r;
        if (grow < M) {
            float4 v = *((const float4*)(myc + r * 132 + c * 4));
            float s = dinv[grow];
            uint2 p;
            p.x = (unsigned)f2bf(v.x * s) | ((unsigned)f2bf(v.y * s) << 16);
            p.y = (unsigned)f2bf(v.z * s) | ((unsigned)f2bf(v.w * s) << 16);
            ((uint2*)G)[(size_t)(c >> 3) * NN * 8 + (size_t)grow * 8 + (c & 7)] = p;
        }
    }
}

// ---------------- MFMA GEMM layer 2: G = bf16((Xbf16 @ W2) * dinv[row]) ----
// A read from slab-major h1 (4 slabs x [N][32] bf16); output 2 slabs of 32 cols.

__global__ __launch_bounds__(256) void k_gemm64m(const unsigned short* __restrict__ X,
                                                 const unsigned short* __restrict__ W2t,
                                                 const float* __restrict__ dinv,
                                                 unsigned* __restrict__ G, int M) {
    __shared__ float cls[4 * 16 * 68];
    const int t = threadIdx.x;
    const int w = t >> 6, lane = t & 63;
    const int quad = lane >> 4, m16 = lane & 15;
    const int row0 = blockIdx.x * 64 + w * 16;
    int arow = row0 + m16; if (arow >= M) arow = M - 1;

    short8 afrag[4];
#pragma unroll
    for (int ks = 0; ks < 4; ++ks)      // cols ks*32 + quad*8: slab = ks
        afrag[ks] = *((const short8*)(X + (size_t)ks * NN * 32 + (size_t)arow * 32 + quad * 8));

    float* myc = cls + w * 16 * 68;
#pragma unroll
    for (int nt = 0; nt < 4; ++nt) {
        float4v acc = {0.f, 0.f, 0.f, 0.f};
#pragma unroll
        for (int ks = 0; ks < 4; ++ks) {
            const short8 b = *((const short8*)(W2t + (size_t)(nt * 16 + m16) * 128 + ks * 32 + quad * 8));
            acc = __builtin_amdgcn_mfma_f32_16x16x32_bf16(afrag[ks], b, acc, 0, 0, 0);
        }
#pragma unroll
        for (int r = 0; r < 4; ++r)
            myc[(quad * 4 + r) * 68 + nt * 16 + m16] = acc[r];
    }
    __syncthreads();
#pragma unroll
    for (int i = 0; i < 4; ++i) {
        int idx = i * 64 + lane;
        int r = idx >> 4, c = idx & 15;
        int grow = row0 + r;
        if (grow < M) {
            float4 v = *((const float4*)(myc + r * 68 + c * 4));
            float s = dinv[grow];
            uint2 p;
            p.x = (unsigned)f2bf(v.x * s) | ((unsigned)f2bf(v.y * s) << 16);
            p.y = (unsigned)f2bf(v.z * s) | ((unsigned)f2bf(v.w * s) << 16);
            ((uint2*)G)[(size_t)(c >> 3) * NN * 8 + (size_t)grow * 8 + (c & 7)] = p;
        }
    }
}

// ---------------- half-split sliced gather -------------------------------
// Pass HALF=0 aggregates edges with src<NH (slab-half = 3.2 MB -> L2-resident
// per XCD), writes fp32 partials; HALF=1 does src>=NH, adds partials,
// applies dinv/bias(/relu), stores final.  LAYER 1 additionally splits the
// dst-node range in two ([nbase,nend)) so partials fit in 25.6 MB of dead
// workspace (Pa = g2b region: slices 0-1; Pb = ebuf region: slices 2-3).
// LAYER 2 partials live in-place in the fp32 output.
// 8 nodes/wave, 8 lanes/node (64-B row = 8 x uint2); slab loads exec-mask
// predicated so finished node slots issue no requests.

__device__ __forceinline__ int2 ld_seg(const int2* __restrict__ seg, int node, int nend) {
    int2 r = make_int2(0, 0);
    if (node < nend) {
        long long v = __builtin_nontemporal_load((const long long*)(seg + node));
        r.x = (int)(v & 0xffffffffll);
        r.y = (int)(v >> 32);
    }
    return r;
}
__device__ __forceinline__ int ld_csr8(const int* __restrict__ csr, int b, int d, int off) {
    int o = (off < d) ? off : (d > 0 ? d - 1 : 0);
    return __builtin_nontemporal_load(csr + b + o);
}

template<int LAYER, int HALF>
__global__ __launch_bounds__(256) void k_gather_h(
        const int2* __restrict__ seg, const int* __restrict__ csr,
        const unsigned* __restrict__ Gall, const float* __restrict__ dinv,
        const float* __restrict__ bias, float* __restrict__ Pa,
        float* __restrict__ Pb, unsigned* __restrict__ OUT,
        int nbase, int nend) {
    const int lane = threadIdx.x & 63;
    const int w = threadIdx.x >> 6;
    const int l8 = lane & 7;                  // uint2 chunk within 64-B row
    const int shb = lane & 56;                // shfl base = node-slot * 8

    int slice, wis, stride;
    if (LAYER == 1) {                         // 4 slices, XCD pair each
        slice = (blockIdx.x & 7) >> 1;
        wis = (blockIdx.x >> 3) * 8 + (blockIdx.x & 1) * 4 + w;
        stride = 2048;                        // waves per slice
    } else {                                  // 2 slices, XCD quad each
        slice = (blockIdx.x & 7) >> 2;
        wis = (blockIdx.x >> 3) * 16 + (blockIdx.x & 3) * 4 + w;
        stride = 4096;
    }
    const int iter_nodes = stride * 8;
    const uint2* slab = (const uint2*)(Gall + (size_t)slice * NN * 16);  // [N][8] uint2
    float* Pbase = (LAYER == 1)
        ? ((slice < 2 ? Pa : Pb) + (size_t)(slice & 1) * NNH2 * 32)
        : nullptr;

    int node = nbase + wis * 8 + (lane >> 3);
    int2 sg_cur = ld_seg(seg, node, nend);
    int2 sg_nx  = ld_seg(seg, node + iter_nodes, nend);
    int idx_cur = ld_csr8(csr, sg_cur.x, sg_cur.y - sg_cur.x, l8);

    for (; node < nend; node += iter_nodes) {
        const int2 sg = sg_cur;
        int idx = idx_cur;
        sg_cur = sg_nx;                                   // rotate pipeline
        sg_nx  = ld_seg(seg, node + 2 * iter_nodes, nend);
        idx_cur = ld_csr8(csr, sg_cur.x, sg_cur.y - sg_cur.x, l8);

        const int deg = sg.y - sg.x;
        int idx2 = (deg > 8) ? ld_csr8(csr, sg.x, deg, 8 + l8) : 0;

        float a0 = 0.f, a1 = 0.f, a2 = 0.f, a3 = 0.f;
        int wb = 0;
        bool done = false;
        while (!done) {
#pragma unroll
            for (int hw = 0; hw < 2 && !done; ++hw) {     // two 8-edge windows
                const int hidx = hw ? idx2 : idx;
#pragma unroll
                for (int g = 0; g < 2 && !done; ++g) {
#pragma unroll
                    for (int st = 0; st < 4; ++st) {      // 4 independent loads
                        int ew = g * 4 + st;              // 0..7 within window
                        int e = wb + hw * 8 + ew;
                        int s = __shfl(hidx, shb | ew, 64);
                        if (e < deg) {                    // PREDICATED load
                            uint2 v = slab[(size_t)s * 8 + l8];
                            a0 += bfl(v.x); a1 += bfh(v.x);
                            a2 += bfl(v.y); a3 += bfh(v.y);
                        }
                    }
                    if (!__any(wb + hw * 8 + (g + 1) * 4 < deg)) done = true;
                }
            }
            if (!done) {
                wb += 16;
                if (wb >= BCAP) break;                    // hard bound
                idx  = ld_csr8(csr, sg.x, deg, wb + l8);  // rare: deg > 16
                idx2 = (deg > wb + 8) ? ld_csr8(csr, sg.x, deg, wb + 8 + l8) : 0;
            }
        }
        // self-loop in the pass that owns this node's half (row is resident)
        const bool selfhere = (HALF == 0) ? (node < NH) : (node >= NH);
        if (selfhere) {
            uint2 vs = slab[(size_t)node * 8 + l8];
            a0 += bfl(vs.x); a1 += bfh(vs.x); a2 += bfl(vs.y); a3 += bfh(vs.y);
        }
        if (LAYER == 1) {
            float* Pp = Pbase + (size_t)(node - nbase) * 32 + l8 * 4;
            if (HALF == 0) {
                float4n r = {a0, a1, a2, a3};
                __builtin_nontemporal_store(r, (float4n*)Pp);
            } else {
                float4n p = __builtin_nontemporal_load((const float4n*)Pp);
                const float di = __builtin_nontemporal_load(dinv + node);
                const float4 bv = ((const float4*)bias)[slice * 8 + l8];
                float r0 = fmaf(a0 + p.x, di, bv.x), r1 = fmaf(a1 + p.y, di, bv.y);
                float r2 = fmaf(a2 + p.z, di, bv.z), r3 = fmaf(a3 + p.w, di, bv.w);
                r0 = fmaxf(r0, 0.f); r1 = fmaxf(r1, 0.f);
                r2 = fmaxf(r2, 0.f); r3 = fmaxf(r3, 0.f);
                uint2 o;
                o.x = (unsigned)f2bf(r0) | ((unsigned)f2bf(r1) << 16);
                o.y = (unsigned)f2bf(r2) | ((unsigned)f2bf(r3) << 16);
                ((uint2*)OUT)[(size_t)slice * NN * 8 + (size_t)node * 8 + l8] = o;
            }
        } else {
            float* Pp = (float*)OUT + (size_t)node * 64 + slice * 32 + l8 * 4;
            if (HALF == 0) {
                float4n r = {a0, a1, a2, a3};
                __builtin_nontemporal_store(r, (float4n*)Pp);
            } else {
                float4n p = __builtin_nontemporal_load((const float4n*)Pp);
                const float di = __builtin_nontemporal_load(dinv + node);
                const float4 bv = ((const float4*)bias)[slice * 8 + l8];
                float4n r;
                r.x = fmaf(a0 + p.x, di, bv.x);
                r.y = fmaf(a1 + p.y, di, bv.y);
                r.z = fmaf(a2 + p.z, di, bv.z);
                r.w = fmaf(a3 + p.w, di, bv.w);
                *(float4n*)Pp = r;
            }
        }
    }
}

// ---------------- launch ----------------

extern "C" void kernel_launch(void* const* d_in, const int* in_sizes, int n_in,
                              void* d_out, int out_size, void* d_ws, size_t ws_size,
                              hipStream_t stream) {
    const float* x  = (const float*)d_in[0];
    const float* W1 = (const float*)d_in[1];
    const float* b1 = (const float*)d_in[2];
    const float* W2 = (const float*)d_in[3];
    const float* b2 = (const float*)d_in[4];
    const int*   ei = (const int*)d_in[5];   // [2, E] int32
    const int* src = ei;
    const int* dst = ei + EE;
    float* out = (float*)d_out;

    // ws layout — identical footprint to the r3-proven ~91 MB layout.
    // L1 partials overlay DEAD regions: Pa = g2b (written only later by
    // k_gemm64m), Pb = ebuf (dead after k_csr).  Each holds 2 slices x
    // 50000 nodes x 32 floats = 12.8 MB, exact fit.
    char* p = (char*)d_ws;
    unsigned* g1b = (unsigned*)p;             p += (size_t)NN * 64 * 4;  // 25.6MB
    unsigned* h1b = (unsigned*)p;             p += (size_t)NN * 64 * 4;  // 25.6MB
    unsigned* g2b = (unsigned*)p;             p += (size_t)NN * 32 * 4;  // 12.8MB
    unsigned short* w1t = (unsigned short*)p; p += 16384 * 2;
    unsigned short* w2t = (unsigned short*)p; p += 8192 * 2;
    int2*  seg0 = (int2*)p;                   p += (size_t)NN * 8;
    int2*  seg1 = (int2*)p;                   p += (size_t)NN * 8;
    float* dinv = (float*)p;                  p += (size_t)NN * 4;
    int*   bcur = (int*)p;                    p += ((size_t)NB * 4 + 15) & ~(size_t)15;
    int*   csr  = (int*)p;                    p += (size_t)NB * BCAP * 4; // 12.8MB
    int*   ebuf = (int*)p;                                                // 12.8MB (dead after k_csr)
    float* Pa   = (float*)g2b;                // L1 partials, slices 0-1
    float* Pb   = (float*)ebuf;               // L1 partials, slices 2-3

    constexpr int IB = (24576 + NB + 255) / 256;  // init blocks

    k_init<<<IB, 256, 0, stream>>>(W1, W2, w1t, w2t, bcur);
    k_bin<<<(EE + TILE - 1) / TILE, 256, 0, stream>>>(src, dst, bcur, ebuf, EE);
    k_csr<<<NB, 256, 0, stream>>>(bcur, ebuf, seg0, seg1, dinv, csr, NN);

    // layer 1: g1b = bf16((x@W1)*dinv) ; h1b = bf16(relu(dinv*(agg+g1)+b1))
    k_gemm128m<<<(NN + 63) / 64, 256, 0, stream>>>(x, w1t, dinv, g1b, NN);
    // dst-range 0
    k_gather_h<1, 0><<<GB, 256, 0, stream>>>(seg0, csr, g1b, dinv, b1, Pa, Pb, h1b, 0, NNH2);
    k_gather_h<1, 1><<<GB, 256, 0, stream>>>(seg1, csr, g1b, dinv, b1, Pa, Pb, h1b, 0, NNH2);
    // dst-range 1
    k_gather_h<1, 0><<<GB, 256, 0, stream>>>(seg0, csr, g1b, dinv, b1, Pa, Pb, h1b, NNH2, NN);
    k_gather_h<1, 1><<<GB, 256, 0, stream>>>(seg1, csr, g1b, dinv, b1, Pa, Pb, h1b, NNH2, NN);

    // layer 2: g2b = bf16((h1b@W2)*dinv) ; out = dinv*(agg+g2)+b2  [fp32]
    k_gemm64m<<<(NN + 63) / 64, 256, 0, stream>>>((const unsigned short*)h1b, w2t, dinv, g2b, NN);
    k_gather_h<2, 0><<<GB, 256, 0, stream>>>(seg0, csr, g2b, dinv, b2, Pa, Pb, (unsigned*)out, 0, NN);
    k_gather_h<2, 1><<<GB, 256, 0, stream>>>(seg1, csr, g2b, dinv, b2, Pa, Pb, (unsigned*)out, 0, NN);
}